// Round 5
// baseline (523.418 us; speedup 1.0000x reference)
//
#include <hip/hip_runtime.h>

// ---------------- ws layout (float indices) ----------------
#define WS_GT    0       // float gT[512][8]  (gamma .* Wpre, transposed [k][j])
#define WS_G     4096    // float G[8]
#define WS_K     4104    // float K[8]
#define WS_COEF  4112    // float coef[nU]  (<= 672)

// ================= compile-time Pauli-term tables =================
// Pauli letters, 2 bits/qubit: 0=I, 1=X, 2=Z, 3=Y
constexpr void conj_cnot_ce(unsigned &pat, int &sg, int c, int t) {
  unsigned wc = (pat >> (2 * c)) & 3u;
  unsigned wt = (pat >> (2 * t)) & 3u;
  unsigned k = 4u * wc + wt;
  unsigned nc = (0x5F0AF5A0u >> (2u * k)) & 3u;
  unsigned nt = (0xB1E4B1E4u >> (2u * k)) & 3u;
  if ((0x8040u >> k) & 1u) sg = -sg;
  pat &= ~((3u << (2 * c)) | (3u << (2 * t)));
  pat |= (nc << (2 * c)) | (nt << (2 * t));
}
constexpr void conj_ring_ce(unsigned &pat, int &sg) {
  for (int g = 0; g < 8; ++g) {
    int c = 7 - g, t = (c + 1) & 7;
    conj_cnot_ce(pat, sg, c, t);
  }
}

#define MAX_RAW 672
struct CT {
  int nU, nR;
  unsigned short upat[MAX_RAW];
  int ustart[MAX_RAW + 1];
  short rsign[MAX_RAW];
  unsigned char rwi[MAX_RAW];
  unsigned short rcos[MAX_RAW];
  unsigned short rsin[MAX_RAW];
};

constexpr CT build_ct() {
  CT T{};
  unsigned short rpat[MAX_RAW] = {};
  short rsgn[MAX_RAW] = {};
  unsigned char rwi_[MAX_RAW] = {};
  unsigned short rc_[MAX_RAW] = {}, rs_[MAX_RAW] = {};
  int nraw = 0;
  for (int o = 0; o < 16; ++o) {
    const int i = o >> 1, p = o & 1;
    unsigned pat = (p ? 1u : 2u) << (2 * i);
    int sg0 = 1;
    conj_ring_ce(pat, sg0);
    int w = 0;
    for (int q = 0; q < 8; ++q)
      if ((pat >> (2 * q)) & 3u) ++w;
    for (int b = 0; b < (1 << w); ++b) {
      int sign = sg0;
      unsigned ce = 0, se = 0;
      if (p == 0) ce += 1u << (2 * i);
      else { se += 1u << (2 * i); sign = -sign; }
      unsigned np = 0;
      int j = 0;
      for (int q = 0; q < 8; ++q) {
        unsigned L = (pat >> (2 * q)) & 3u;
        if (!L) continue;
        int bb = (b >> j) & 1;
        ++j;
        if (L == 2u) {
          if (bb) { np |= 1u << (2 * q); se += 1u << (2 * q); sign = -sign; }
          else    { np |= 2u << (2 * q); ce += 1u << (2 * q); }
        } else {
          if (bb) { np |= 2u << (2 * q); se += 1u << (2 * q); }
          else    { np |= 1u << (2 * q); ce += 1u << (2 * q); }
        }
      }
      int sg2 = 1;
      conj_ring_ce(np, sg2);
      sign *= sg2;
      bool hasY = false;
      for (int q = 0; q < 8; ++q)
        if (((np >> (2 * q)) & 3u) == 3u) hasY = true;
      if (hasY) continue;  // <Y>=0 exactly for real product states
      rpat[nraw] = (unsigned short)np;
      rsgn[nraw] = (short)sign;
      rwi_[nraw] = (unsigned char)i;
      rc_[nraw] = (unsigned short)ce;
      rs_[nraw] = (unsigned short)se;
      ++nraw;
    }
  }
  int map_[65536];
  for (int x = 0; x < 65536; ++x) map_[x] = -1;
  int uid[MAX_RAW] = {};
  int cnt[MAX_RAW] = {};
  int nU = 0;
  for (int r = 0; r < nraw; ++r) {
    int pp = rpat[r];
    if (map_[pp] < 0) { map_[pp] = nU; T.upat[nU] = (unsigned short)pp; ++nU; }
    uid[r] = map_[pp];
    cnt[uid[r]]++;
  }
  T.ustart[0] = 0;
  for (int u = 0; u < nU; ++u) T.ustart[u + 1] = T.ustart[u] + cnt[u];
  int fill[MAX_RAW] = {};
  for (int u = 0; u < nU; ++u) fill[u] = T.ustart[u];
  for (int r = 0; r < nraw; ++r) {
    int pos = fill[uid[r]]++;
    T.rsign[pos] = rsgn[r];
    T.rwi[pos] = rwi_[r];
    T.rcos[pos] = rc_[r];
    T.rsin[pos] = rs_[r];
  }
  T.nU = nU;
  T.nR = nraw;
  return T;
}

static constexpr CT kT = build_ct();

// ================= init kernel =================
__global__ void qsco_init_kernel(const float* __restrict__ ln_gamma,
                                 const float* __restrict__ ln_beta,
                                 const float* __restrict__ Wpre,
                                 const float* __restrict__ bpre,
                                 const float* __restrict__ theta,
                                 const float* __restrict__ Wpost,
                                 float* __restrict__ ws) {
  const int tid = threadIdx.x;
  for (int i = tid; i < 4096; i += 256) {
    int k = i >> 3, j = i & 7;
    ws[WS_GT + i] = ln_gamma[k] * Wpre[j * 512 + k];
  }
  {
    const int j = tid >> 5, l = tid & 31;
    float gs = 0.f, ks = 0.f;
    for (int t = 0; t < 16; ++t) {
      int k = l * 16 + t;
      float w = Wpre[j * 512 + k];
      gs = fmaf(ln_gamma[k], w, gs);
      ks = fmaf(ln_beta[k], w, ks);
    }
    for (int m = 1; m <= 16; m <<= 1) {
      gs += __shfl_xor(gs, m, 64);
      ks += __shfl_xor(ks, m, 64);
    }
    if (l == 0) {
      ws[WS_G + j] = gs;
      ws[WS_K + j] = ks + bpre[j];
    }
  }
  float cth[8], sth[8];
#pragma unroll
  for (int q = 0; q < 8; ++q) {
    cth[q] = __cosf(theta[q]);
    sth[q] = __sinf(theta[q]);
  }
  for (int u = tid; u < kT.nU; u += 256) {
    float sum = 0.f;
    for (int r = kT.ustart[u]; r < kT.ustart[u + 1]; ++r) {
      float c = (float)kT.rsign[r] * Wpost[kT.rwi[r]];
      unsigned ce = kT.rcos[r], se = kT.rsin[r];
#pragma unroll
      for (int q = 0; q < 8; ++q) {
        int e1 = (ce >> (2 * q)) & 3;
        int e2 = (se >> (2 * q)) & 3;
        if (e1 >= 1) c *= cth[q];
        if (e1 == 2) c *= cth[q];
        if (e2 >= 1) c *= sth[q];
        if (e2 == 2) c *= sth[q];
      }
      sum += c;
    }
    ws[WS_COEF + u] = sum;
  }
}

// ================= main kernel =================
// 4 waves/block: wave = (row-group rg = w>>1) x (k-half kh = w&1).
// Each wave: 64 rows (lane = row) x 256 cols, staged through a single
// wave-private LDS buffer (64 x 34 dwords = 8704 B) in 32-col chunks.
// Global loads are full 128B lines: instr ii covers rows lane>>3 + 8*ii,
// lane&7 picks the 16B segment. Two chunk register buffers give the
// load -> ds_write distance ~1 full compute-chunk; DS in-order per wave
// makes the single LDS buffer safe (reads of chunk c precede writes of c+1).
#define TSD 34

__global__ __launch_bounds__(256, 4) void qsco_main_kernel(
    const float* __restrict__ E,
    const float* __restrict__ ws,
    const float* __restrict__ bpost,
    float* __restrict__ out,
    int nrows) {
  __shared__ float tile[4][64 * TSD];  // 34816 B/block
  const int lane = threadIdx.x & 63;
  const int w = threadIdx.x >> 6;
  const int rg = w >> 1;
  const int kh = w & 1;
  const int r0 = blockIdx.x * 128 + rg * 64;
  const int kb = kh * 256;
  float* tl = &tile[w][0];

  const int lrow = lane >> 3, lcol = lane & 7;
  const float* gbase[8];
#pragma unroll
  for (int ii = 0; ii < 8; ++ii) {
    int rr = min(r0 + lrow + 8 * ii, nrows - 1);
    gbase[ii] = E + (size_t)rr * 512 + kb + lcol * 4;
  }
  float* stbase = tl + TSD * lrow + 4 * lcol;
  const float* rdbase = tl + TSD * lane;
  const float* gT = ws + WS_GT;

  float s0 = 0.f, s1 = 0.f;
  float d[8];
#pragma unroll
  for (int j = 0; j < 8; ++j) d[j] = 0.f;

  float4 A[8], B[8];

#define LOAD32(dst, c)                                                     \
  { _Pragma("unroll") for (int ii = 0; ii < 8; ++ii)                       \
      dst[ii] = *(const float4*)(gbase[ii] + 32 * (c)); }
#define STORE32(src)                                                       \
  { _Pragma("unroll") for (int ii = 0; ii < 8; ++ii) {                     \
      float* p = stbase + 272 * ii;                                        \
      *(float2*)(p) = make_float2(src[ii].x, src[ii].y);                   \
      *(float2*)(p + 2) = make_float2(src[ii].z, src[ii].w); } }
#define COMPUTE32(c)                                                       \
  { _Pragma("unroll") for (int kk = 0; kk < 32; kk += 2) {                 \
      float2 e2 = *(const float2*)(rdbase + kk);                           \
      const float* gk = gT + (kb + 32 * (c) + kk) * 8;                     \
      s0 += e2.x + e2.y;                                                   \
      s1 = fmaf(e2.x, e2.x, fmaf(e2.y, e2.y, s1));                         \
      _Pragma("unroll") for (int j = 0; j < 8; ++j)                        \
        d[j] = fmaf(e2.y, gk[8 + j], fmaf(e2.x, gk[j], d[j])); } }

  LOAD32(A, 0)
  LOAD32(B, 1)
  STORE32(A)       // chunk 0 -> LDS (vmcnt wait: initial fill, unavoidable)
#pragma unroll
  for (int c = 0; c < 8; ++c) {
    if (c + 2 < 8) {
      if (c & 1) { LOAD32(B, c + 2) } else { LOAD32(A, c + 2) }
    }
    COMPUTE32(c)   // reads chunk c (in-order DS: precedes next write)
    if (c + 1 < 8) {
      if (c & 1) { STORE32(A) } else { STORE32(B) }  // chunk c+1 -> LDS
    }
  }

  // combine k-halves: odd wave ships partials to even wave via its tile
  if (kh == 1) {
#pragma unroll
    for (int j = 0; j < 8; ++j) tl[lane * 12 + j] = d[j];
    tl[lane * 12 + 8] = s0;
    tl[lane * 12 + 9] = s1;
  }
  __syncthreads();
  if (kh == 0) {
    const float* pp = &tile[w + 1][0];
#pragma unroll
    for (int j = 0; j < 8; ++j) d[j] += pp[lane * 12 + j];
    s0 += pp[lane * 12 + 8];
    s1 += pp[lane * 12 + 9];

    const float mu = s0 * (1.0f / 512.0f);
    const float var = s1 * (1.0f / 512.0f) - mu * mu;
    const float rstd = rsqrtf(var + 1e-5f);

    const float* Gp = ws + WS_G;
    const float* Kp = ws + WS_K;
    float cA[8], sA[8];
#pragma unroll
    for (int j = 0; j < 8; ++j) {
      float ang = rstd * (d[j] - mu * Gp[j]) + Kp[j];
      cA[j] = __cosf(ang);
      sA[j] = __sinf(ang);
    }

    const float* cf = ws + WS_COEF;
    float acc0 = bpost[0], acc1 = 0.f, acc2 = 0.f, acc3 = 0.f;
#pragma unroll
    for (int u = 0; u < kT.nU; ++u) {
      const unsigned pat = kT.upat[u];  // immediate after unroll
      float prod = cf[u];
#pragma unroll
      for (int q = 0; q < 8; ++q) {
        const unsigned L = (pat >> (2 * q)) & 3u;
        if (L == 1u) prod *= sA[q];
        else if (L == 2u) prod *= cA[q];
      }
      if ((u & 3) == 0) acc0 += prod;
      else if ((u & 3) == 1) acc1 += prod;
      else if ((u & 3) == 2) acc2 += prod;
      else acc3 += prod;
    }
    const float v = (acc0 + acc1) + (acc2 + acc3);
    const int myRow = r0 + lane;
    if (myRow < nrows) out[myRow] = v;
  }

#undef LOAD32
#undef STORE32
#undef COMPUTE32
}

extern "C" void kernel_launch(void* const* d_in, const int* in_sizes, int n_in,
                              void* d_out, int out_size, void* d_ws, size_t ws_size,
                              hipStream_t stream) {
  const float* E        = (const float*)d_in[0];
  const float* ln_gamma = (const float*)d_in[1];
  const float* ln_beta  = (const float*)d_in[2];
  const float* Wpre     = (const float*)d_in[3];
  const float* bpre     = (const float*)d_in[4];
  const float* theta    = (const float*)d_in[5];
  const float* Wpost    = (const float*)d_in[6];
  const float* bpost    = (const float*)d_in[7];
  float* out = (float*)d_out;
  float* ws = (float*)d_ws;

  const int nrows = in_sizes[0] / 512;

  qsco_init_kernel<<<1, 256, 0, stream>>>(ln_gamma, ln_beta, Wpre, bpre, theta,
                                          Wpost, ws);

  const int blocks = (nrows + 127) / 128;
  qsco_main_kernel<<<blocks, 256, 0, stream>>>(E, ws, bpost, out, nrows);
}

// Round 6
// 484.543 us; speedup vs baseline: 1.0802x; 1.0802x over previous
//
#include <hip/hip_runtime.h>

// ---------------- ws layout (float indices) ----------------
#define WS_GT    0       // float gT[512][8]  (gamma .* Wpre, transposed [k][j])
#define WS_G     4096    // float G[8]
#define WS_K     4104    // float K[8]
#define WS_COEF  4112    // float coef[nU]  (<= 672)

// ================= compile-time Pauli-term tables =================
// Pauli letters, 2 bits/qubit: 0=I, 1=X, 2=Z, 3=Y
constexpr void conj_cnot_ce(unsigned &pat, int &sg, int c, int t) {
  unsigned wc = (pat >> (2 * c)) & 3u;
  unsigned wt = (pat >> (2 * t)) & 3u;
  unsigned k = 4u * wc + wt;
  unsigned nc = (0x5F0AF5A0u >> (2u * k)) & 3u;
  unsigned nt = (0xB1E4B1E4u >> (2u * k)) & 3u;
  if ((0x8040u >> k) & 1u) sg = -sg;
  pat &= ~((3u << (2 * c)) | (3u << (2 * t)));
  pat |= (nc << (2 * c)) | (nt << (2 * t));
}
constexpr void conj_ring_ce(unsigned &pat, int &sg) {
  for (int g = 0; g < 8; ++g) {
    int c = 7 - g, t = (c + 1) & 7;
    conj_cnot_ce(pat, sg, c, t);
  }
}

#define MAX_RAW 672
struct CT {
  int nU, nR;
  unsigned short upat[MAX_RAW];
  int ustart[MAX_RAW + 1];
  short rsign[MAX_RAW];
  unsigned char rwi[MAX_RAW];
  unsigned short rcos[MAX_RAW];
  unsigned short rsin[MAX_RAW];
};

constexpr CT build_ct() {
  CT T{};
  unsigned short rpat[MAX_RAW] = {};
  short rsgn[MAX_RAW] = {};
  unsigned char rwi_[MAX_RAW] = {};
  unsigned short rc_[MAX_RAW] = {}, rs_[MAX_RAW] = {};
  int nraw = 0;
  for (int o = 0; o < 16; ++o) {
    const int i = o >> 1, p = o & 1;
    unsigned pat = (p ? 1u : 2u) << (2 * i);
    int sg0 = 1;
    conj_ring_ce(pat, sg0);
    int w = 0;
    for (int q = 0; q < 8; ++q)
      if ((pat >> (2 * q)) & 3u) ++w;
    for (int b = 0; b < (1 << w); ++b) {
      int sign = sg0;
      unsigned ce = 0, se = 0;
      if (p == 0) ce += 1u << (2 * i);
      else { se += 1u << (2 * i); sign = -sign; }
      unsigned np = 0;
      int j = 0;
      for (int q = 0; q < 8; ++q) {
        unsigned L = (pat >> (2 * q)) & 3u;
        if (!L) continue;
        int bb = (b >> j) & 1;
        ++j;
        if (L == 2u) {
          if (bb) { np |= 1u << (2 * q); se += 1u << (2 * q); sign = -sign; }
          else    { np |= 2u << (2 * q); ce += 1u << (2 * q); }
        } else {
          if (bb) { np |= 2u << (2 * q); se += 1u << (2 * q); }
          else    { np |= 1u << (2 * q); ce += 1u << (2 * q); }
        }
      }
      int sg2 = 1;
      conj_ring_ce(np, sg2);
      sign *= sg2;
      bool hasY = false;
      for (int q = 0; q < 8; ++q)
        if (((np >> (2 * q)) & 3u) == 3u) hasY = true;
      if (hasY) continue;  // <Y>=0 exactly for real product states
      rpat[nraw] = (unsigned short)np;
      rsgn[nraw] = (short)sign;
      rwi_[nraw] = (unsigned char)i;
      rc_[nraw] = (unsigned short)ce;
      rs_[nraw] = (unsigned short)se;
      ++nraw;
    }
  }
  int map_[65536];
  for (int x = 0; x < 65536; ++x) map_[x] = -1;
  int uid[MAX_RAW] = {};
  int cnt[MAX_RAW] = {};
  int nU = 0;
  for (int r = 0; r < nraw; ++r) {
    int pp = rpat[r];
    if (map_[pp] < 0) { map_[pp] = nU; T.upat[nU] = (unsigned short)pp; ++nU; }
    uid[r] = map_[pp];
    cnt[uid[r]]++;
  }
  T.ustart[0] = 0;
  for (int u = 0; u < nU; ++u) T.ustart[u + 1] = T.ustart[u] + cnt[u];
  int fill[MAX_RAW] = {};
  for (int u = 0; u < nU; ++u) fill[u] = T.ustart[u];
  for (int r = 0; r < nraw; ++r) {
    int pos = fill[uid[r]]++;
    T.rsign[pos] = rsgn[r];
    T.rwi[pos] = rwi_[r];
    T.rcos[pos] = rc_[r];
    T.rsin[pos] = rs_[r];
  }
  T.nU = nU;
  T.nR = nraw;
  return T;
}

static constexpr CT kT = build_ct();

// ================= init kernel =================
__global__ void qsco_init_kernel(const float* __restrict__ ln_gamma,
                                 const float* __restrict__ ln_beta,
                                 const float* __restrict__ Wpre,
                                 const float* __restrict__ bpre,
                                 const float* __restrict__ theta,
                                 const float* __restrict__ Wpost,
                                 float* __restrict__ ws) {
  const int tid = threadIdx.x;
  for (int i = tid; i < 4096; i += 256) {
    int k = i >> 3, j = i & 7;
    ws[WS_GT + i] = ln_gamma[k] * Wpre[j * 512 + k];
  }
  {
    const int j = tid >> 5, l = tid & 31;
    float gs = 0.f, ks = 0.f;
    for (int t = 0; t < 16; ++t) {
      int k = l * 16 + t;
      float w = Wpre[j * 512 + k];
      gs = fmaf(ln_gamma[k], w, gs);
      ks = fmaf(ln_beta[k], w, ks);
    }
    for (int m = 1; m <= 16; m <<= 1) {
      gs += __shfl_xor(gs, m, 64);
      ks += __shfl_xor(ks, m, 64);
    }
    if (l == 0) {
      ws[WS_G + j] = gs;
      ws[WS_K + j] = ks + bpre[j];
    }
  }
  float cth[8], sth[8];
#pragma unroll
  for (int q = 0; q < 8; ++q) {
    cth[q] = __cosf(theta[q]);
    sth[q] = __sinf(theta[q]);
  }
  for (int u = tid; u < kT.nU; u += 256) {
    float sum = 0.f;
    for (int r = kT.ustart[u]; r < kT.ustart[u + 1]; ++r) {
      float c = (float)kT.rsign[r] * Wpost[kT.rwi[r]];
      unsigned ce = kT.rcos[r], se = kT.rsin[r];
#pragma unroll
      for (int q = 0; q < 8; ++q) {
        int e1 = (ce >> (2 * q)) & 3;
        int e2 = (se >> (2 * q)) & 3;
        if (e1 >= 1) c *= cth[q];
        if (e1 == 2) c *= cth[q];
        if (e2 >= 1) c *= sth[q];
        if (e2 == 2) c *= sth[q];
      }
      sum += c;
    }
    ws[WS_COEF + u] = sum;
  }
}

// ================= main kernel =================
// Block = 64 rows; wave w covers k-quarter [128w, 128w+128) in 4 chunks of
// 32 cols. Each global load instr = 8 rows x one full 128B line (lane>>3 =
// row-in-group, lane&7 = 16B segment): no half-line over-fetch. Single
// in-flight register chunk A[8] (32 VGPRs) -> no spill. Single wave-private
// LDS chunk buffer (64 x 34 dwords; per-wave DS in-order makes reuse safe).
// Partials combined across waves via LDS (stride 11, conflict-free) + one
// barrier; wave 0 does LN + trig + compile-time-unrolled Pauli-term sum.
#define TSD 34

__global__ __launch_bounds__(256) void qsco_main_kernel(
    const float* __restrict__ E,
    const float* __restrict__ ws,
    const float* __restrict__ bpost,
    float* __restrict__ out,
    int nrows) {
  __shared__ float tile[4][64 * TSD];  // 34816 B/block -> 4 blocks/CU
  const int lane = threadIdx.x & 63;
  const int w = threadIdx.x >> 6;
  const int r0 = blockIdx.x * 64;
  const int kb = w * 128;
  float* tl = &tile[w][0];

  const int lrow = lane >> 3, lseg = lane & 7;
  const float* gb[8];
#pragma unroll
  for (int ii = 0; ii < 8; ++ii) {
    int rr = min(r0 + 8 * ii + lrow, nrows - 1);
    gb[ii] = E + (size_t)rr * 512 + kb + lseg * 4;
  }
  float* stp = tl + TSD * lrow + 4 * lseg;
  const float* rdp = tl + TSD * lane;
  const float* gT = ws + WS_GT;

  float s0 = 0.f, s1 = 0.f;
  float d[8];
#pragma unroll
  for (int j = 0; j < 8; ++j) d[j] = 0.f;

  float4 A[8];

#define LOAD32(c)                                                          \
  { _Pragma("unroll") for (int ii = 0; ii < 8; ++ii)                       \
      A[ii] = *(const float4*)(gb[ii] + 32 * (c)); }
#define STORE32()                                                          \
  { _Pragma("unroll") for (int ii = 0; ii < 8; ++ii) {                     \
      float* p = stp + 272 * ii;                                           \
      *(float2*)(p) = make_float2(A[ii].x, A[ii].y);                       \
      *(float2*)(p + 2) = make_float2(A[ii].z, A[ii].w); } }
#define COMPUTE32(c)                                                       \
  { _Pragma("unroll") for (int kk = 0; kk < 32; kk += 2) {                 \
      float2 e2 = *(const float2*)(rdp + kk);                              \
      const float* gk = gT + (kb + 32 * (c) + kk) * 8;                     \
      s0 += e2.x + e2.y;                                                   \
      s1 = fmaf(e2.x, e2.x, fmaf(e2.y, e2.y, s1));                        \
      _Pragma("unroll") for (int j = 0; j < 8; ++j)                        \
        d[j] = fmaf(e2.y, gk[8 + j], fmaf(e2.x, gk[j], d[j])); } }

  LOAD32(0)
  STORE32()        // initial fill (vmcnt drain unavoidable once)
  LOAD32(1)
  COMPUTE32(0)     // ~670 cyc between LOAD32(1) issue and STORE32 drain
  STORE32()
  LOAD32(2)
  COMPUTE32(1)
  STORE32()
  LOAD32(3)
  COMPUTE32(2)
  STORE32()
  COMPUTE32(3)

  // combine k-quarter partials: waves 1..3 ship via their tiles (stride 11
  // is odd -> all 32 banks covered, 2-way free)
  if (w != 0) {
#pragma unroll
    for (int j = 0; j < 8; ++j) tl[lane * 11 + j] = d[j];
    tl[lane * 11 + 8] = s0;
    tl[lane * 11 + 9] = s1;
  }
  __syncthreads();
  if (w == 0) {
#pragma unroll
    for (int wv = 1; wv < 4; ++wv) {
      const float* pp = &tile[wv][0];
#pragma unroll
      for (int j = 0; j < 8; ++j) d[j] += pp[lane * 11 + j];
      s0 += pp[lane * 11 + 8];
      s1 += pp[lane * 11 + 9];
    }

    const float mu = s0 * (1.0f / 512.0f);
    const float var = s1 * (1.0f / 512.0f) - mu * mu;
    const float rstd = rsqrtf(var + 1e-5f);

    const float* Gp = ws + WS_G;
    const float* Kp = ws + WS_K;
    float cA[8], sA[8];
#pragma unroll
    for (int j = 0; j < 8; ++j) {
      float ang = rstd * (d[j] - mu * Gp[j]) + Kp[j];
      cA[j] = __cosf(ang);
      sA[j] = __sinf(ang);
    }

    const float* cf = ws + WS_COEF;
    float acc0 = bpost[0], acc1 = 0.f, acc2 = 0.f, acc3 = 0.f;
#pragma unroll
    for (int u = 0; u < kT.nU; ++u) {
      const unsigned pat = kT.upat[u];  // immediate after unroll
      float prod = cf[u];
#pragma unroll
      for (int q = 0; q < 8; ++q) {
        const unsigned L = (pat >> (2 * q)) & 3u;
        if (L == 1u) prod *= sA[q];
        else if (L == 2u) prod *= cA[q];
      }
      if ((u & 3) == 0) acc0 += prod;
      else if ((u & 3) == 1) acc1 += prod;
      else if ((u & 3) == 2) acc2 += prod;
      else acc3 += prod;
    }
    const float v = (acc0 + acc1) + (acc2 + acc3);
    const int myRow = r0 + lane;
    if (myRow < nrows) out[myRow] = v;
  }

#undef LOAD32
#undef STORE32
#undef COMPUTE32
}

extern "C" void kernel_launch(void* const* d_in, const int* in_sizes, int n_in,
                              void* d_out, int out_size, void* d_ws, size_t ws_size,
                              hipStream_t stream) {
  const float* E        = (const float*)d_in[0];
  const float* ln_gamma = (const float*)d_in[1];
  const float* ln_beta  = (const float*)d_in[2];
  const float* Wpre     = (const float*)d_in[3];
  const float* bpre     = (const float*)d_in[4];
  const float* theta    = (const float*)d_in[5];
  const float* Wpost    = (const float*)d_in[6];
  const float* bpost    = (const float*)d_in[7];
  float* out = (float*)d_out;
  float* ws = (float*)d_ws;

  const int nrows = in_sizes[0] / 512;

  qsco_init_kernel<<<1, 256, 0, stream>>>(ln_gamma, ln_beta, Wpre, bpre, theta,
                                          Wpost, ws);

  const int blocks = (nrows + 63) / 64;
  qsco_main_kernel<<<blocks, 256, 0, stream>>>(E, ws, bpost, out, nrows);
}